// Round 2
// baseline (515.755 us; speedup 1.0000x reference)
//
#include <hip/hip_runtime.h>
#include <hip/hip_bf16.h>

// Sizes fixed by the problem
#define BATCH 4
#define NSEQ  1024
#define DIM   768
#define NH    12
#define NKV   4
#define HD    64
#define NTOK  (BATCH*NSEQ)   // 4096

using bf16 = __hip_bfloat16;
typedef __attribute__((ext_vector_type(8))) short short8;
typedef __attribute__((ext_vector_type(4))) float floatx4;

__device__ __forceinline__ float b2f(short x) {
  unsigned u = ((unsigned)(unsigned short)x) << 16;
  return __builtin_bit_cast(float, u);
}
__device__ __forceinline__ unsigned short f2b(float f) {
  unsigned u = __builtin_bit_cast(unsigned, f);
  unsigned r = u + 0x7FFF + ((u >> 16) & 1);   // RNE
  return (unsigned short)(r >> 16);
}
__device__ __forceinline__ unsigned pack2(float a, float b) {
  return (unsigned)f2b(a) | ((unsigned)f2b(b) << 16);
}

// ---------------------------------------------------------------------------
// f32 -> bf16 convert (n multiple of 4)
// ---------------------------------------------------------------------------
__global__ __launch_bounds__(256) void cvt_f32_bf16(const float* __restrict__ src,
                                                    bf16* __restrict__ dst, int n4)
{
  int i = blockIdx.x * 256 + threadIdx.x;
  if (i < n4) {
    float4 f = reinterpret_cast<const float4*>(src)[i];
    ushort4 u;
    u.x = f2b(f.x); u.y = f2b(f.y); u.z = f2b(f.z); u.w = f2b(f.w);
    reinterpret_cast<ushort4*>(dst)[i] = u;
  }
}

// ---------------------------------------------------------------------------
// GEMM: Y[m,n] = sum_k A[m,k]*W[n,k] (+bias[n]); bf16 in, fp32 accum.
// OUT = bf16 (intermediates) or float (final, bias f32).
// 64x64 tile, 4 waves 2x2, each wave 32x32 via 2x2 mfma_f32_16x16x32_bf16.
// ---------------------------------------------------------------------------
template <typename OUT>
__global__ __launch_bounds__(256) void gemm_bt(
    const bf16* __restrict__ A, const bf16* __restrict__ W,
    OUT* __restrict__ Y, const float* __restrict__ bias,
    int M, int Ncols, int K)
{
  __shared__ bf16 As[64][40];   // 80B rows: 16B-aligned, 2-way bank alias (free)
  __shared__ bf16 Bs[64][40];
  const int bn = blockIdx.x, bm = blockIdx.y;
  const int t = threadIdx.x;
  const int wave = t >> 6, lane = t & 63;
  const int wm = wave >> 1, wn = wave & 1;
  const int quad = lane >> 4, lr = lane & 15;

  floatx4 acc[2][2] = {};

  const int arow = t >> 2, aseg = t & 3;    // 64 rows x 4 segs of 8 bf16
  const bf16* Aptr = A + (size_t)(bm * 64 + arow) * K + aseg * 8;
  const bf16* Wptr = W + (size_t)(bn * 64 + arow) * K + aseg * 8;

  for (int k0 = 0; k0 < K; k0 += 32) {
    short8 av = *reinterpret_cast<const short8*>(Aptr + k0);
    short8 wv = *reinterpret_cast<const short8*>(Wptr + k0);
    *reinterpret_cast<short8*>(&As[arow][aseg * 8]) = av;
    *reinterpret_cast<short8*>(&Bs[arow][aseg * 8]) = wv;
    __syncthreads();

    short8 a0 = *reinterpret_cast<const short8*>(&As[wm * 32 + lr][quad * 8]);
    short8 a1 = *reinterpret_cast<const short8*>(&As[wm * 32 + 16 + lr][quad * 8]);
    short8 b0 = *reinterpret_cast<const short8*>(&Bs[wn * 32 + lr][quad * 8]);
    short8 b1 = *reinterpret_cast<const short8*>(&Bs[wn * 32 + 16 + lr][quad * 8]);

    acc[0][0] = __builtin_amdgcn_mfma_f32_16x16x32_bf16(a0, b0, acc[0][0], 0, 0, 0);
    acc[0][1] = __builtin_amdgcn_mfma_f32_16x16x32_bf16(a0, b1, acc[0][1], 0, 0, 0);
    acc[1][0] = __builtin_amdgcn_mfma_f32_16x16x32_bf16(a1, b0, acc[1][0], 0, 0, 0);
    acc[1][1] = __builtin_amdgcn_mfma_f32_16x16x32_bf16(a1, b1, acc[1][1], 0, 0, 0);
    __syncthreads();
  }

  // C/D layout: col = lane&15, row = quad*4 + reg
  for (int tm = 0; tm < 2; ++tm)
    for (int tn = 0; tn < 2; ++tn)
      for (int r = 0; r < 4; ++r) {
        int row = bm * 64 + wm * 32 + tm * 16 + quad * 4 + r;
        int col = bn * 64 + wn * 32 + tn * 16 + lr;
        float v = acc[tm][tn][r];
        if (bias) v += bias[col];
        if constexpr (__is_same(OUT, float)) {
          Y[(size_t)row * Ncols + col] = v;
        } else {
          unsigned short ub = f2b(v);
          *(unsigned short*)&Y[(size_t)row * Ncols + col] = ub;
        }
      }
}

// ---------------------------------------------------------------------------
// RoPE (2D grid positions) + qk-norm, in place on q (4096x1536) and k (4096x512).
// One wave per 64-dim head vector.
// ---------------------------------------------------------------------------
#define NQVEC (NTOK * 2 * NH)    // 98304
#define NKVEC (NTOK * 2 * NKV)   // 32768

__global__ __launch_bounds__(256) void rope_qknorm(bf16* __restrict__ q,
                                                   bf16* __restrict__ k)
{
  int wid = (blockIdx.x * 256 + threadIdx.x) >> 6;
  int lane = threadIdx.x & 63;
  bf16* ptr;
  int token;
  if (wid < NQVEC) {
    token = wid / 24;
    int rem = wid % 24;              // s*12+h
    ptr = q + (size_t)token * 1536 + rem * 64;
  } else {
    int w2 = wid - NQVEC;
    token = w2 / 8;
    int rem = w2 % 8;                // s*4+kvh
    ptr = k + (size_t)token * 512 + rem * 64;
  }
  int n = token & (NSEQ - 1);
  float pos = (lane < 32) ? (float)(n >> 5) : (float)(n & 31);
  int fi = lane & 31;
  float invf = exp2f(-(float)fi * (13.2877123795494f / 32.0f)); // 10000^(-fi/32)
  float theta = pos * invf;
  float sn, cs;
  sincosf(theta, &sn, &cs);

  float val = b2f(*(const short*)&ptr[lane]);
  float partner = __shfl_xor(val, 1);
  float rot = (lane & 1) ? partner : -partner;   // rot[2i]=-x[2i+1], rot[2i+1]=x[2i]
  float r = val * cs + rot * sn;

  float ss = r * r;
  #pragma unroll
  for (int off = 1; off < 64; off <<= 1) ss += __shfl_xor(ss, off);
  float outv = r / (sqrtf(ss) + 1e-6f);
  unsigned short ub = f2b(outv);
  *(unsigned short*)&ptr[lane] = ub;
}

// ---------------------------------------------------------------------------
// Fused windowed attention, both streams + differential combine.
// Block = (b, h, qh): 32 queries of one grid row. 256 thr = 32 q x 8 lanes.
// Writes X = o1/l1 - softplus(lambda_p[h]) * o2/l2 as bf16.
// ---------------------------------------------------------------------------
__global__ __launch_bounds__(256) void attn_fused(
    const bf16* __restrict__ q, const bf16* __restrict__ k,
    const bf16* __restrict__ v1, const bf16* __restrict__ v2,
    const float* __restrict__ lambda_p, bf16* __restrict__ X)
{
  __shared__ float kk1[32][64];
  __shared__ float kk2[32][64];
  __shared__ float vv1s[32][64];
  __shared__ float vv2s[32][64];

  const int bid = blockIdx.x;
  const int qh = bid & 31;
  const int hb = bid >> 5;          // h + 12*b
  const int h  = hb % 12;
  const int b  = hb / 12;
  const int kvh = h / 3;            // GQA repeat=3

  const int t = threadIdx.x;
  const int qw = t >> 3, g = t & 7;
  const int token_q = b * NSEQ + qh * 32 + qw;

  float qv1[8], qv2[8];
  {
    const bf16* qp = q + (size_t)token_q * 1536 + h * 64 + g * 8;
    short8 qa = *reinterpret_cast<const short8*>(qp);
    short8 qb2 = *reinterpret_cast<const short8*>(qp + 768);
    #pragma unroll
    for (int i = 0; i < 8; ++i) { qv1[i] = b2f(qa[i]); qv2[i] = b2f(qb2[i]); }
  }

  float m1 = -1e30f, l1 = 0.f, m2 = -1e30f, l2 = 0.f;
  float o1[8] = {}, o2[8] = {};

  const int kh0 = (qh - 8 < 0) ? 0 : qh - 8;
  const int kh1 = (qh + 8 > 31) ? 31 : qh + 8;

  for (int kh = kh0; kh <= kh1; ++kh) {
    {
      int skw = t >> 3, sd = (t & 7) * 8;
      int token_k = b * NSEQ + kh * 32 + skw;
      short8 k1v = *reinterpret_cast<const short8*>(
          k + (size_t)token_k * 512 + kvh * 64 + sd);
      short8 k2v = *reinterpret_cast<const short8*>(
          k + (size_t)token_k * 512 + 256 + kvh * 64 + sd);
      short8 v1v = *reinterpret_cast<const short8*>(
          v1 + (size_t)token_k * 256 + kvh * 64 + sd);
      short8 v2v = *reinterpret_cast<const short8*>(
          v2 + (size_t)token_k * 256 + kvh * 64 + sd);
      #pragma unroll
      for (int i = 0; i < 8; ++i) {
        kk1[skw][sd + i] = b2f(k1v[i]);
        kk2[skw][sd + i] = b2f(k2v[i]);
        vv1s[skw][sd + i] = b2f(v1v[i]);
        vv2s[skw][sd + i] = b2f(v2v[i]);
      }
    }
    __syncthreads();

    const int w0 = (qw - 8 < 0) ? 0 : qw - 8;
    const int w1 = (qw + 8 > 31) ? 31 : qw + 8;
    for (int kw = w0; kw <= w1; ++kw) {
      float p1 = 0.f, p2 = 0.f;
      #pragma unroll
      for (int i = 0; i < 8; ++i) {
        p1 += qv1[i] * kk1[kw][g * 8 + i];
        p2 += qv2[i] * kk2[kw][g * 8 + i];
      }
      p1 += __shfl_xor(p1, 1); p1 += __shfl_xor(p1, 2); p1 += __shfl_xor(p1, 4);
      p2 += __shfl_xor(p2, 1); p2 += __shfl_xor(p2, 2); p2 += __shfl_xor(p2, 4);
      float s1 = p1 * 0.125f, s2 = p2 * 0.125f;   // 1/sqrt(64)

      float mn1 = fmaxf(m1, s1);
      float c1 = __expf(m1 - mn1), pe1 = __expf(s1 - mn1);
      l1 = l1 * c1 + pe1;
      float mn2 = fmaxf(m2, s2);
      float c2 = __expf(m2 - mn2), pe2 = __expf(s2 - mn2);
      l2 = l2 * c2 + pe2;
      #pragma unroll
      for (int i = 0; i < 8; ++i) {
        o1[i] = o1[i] * c1 + pe1 * vv1s[kw][g * 8 + i];
        o2[i] = o2[i] * c2 + pe2 * vv2s[kw][g * 8 + i];
      }
      m1 = mn1; m2 = mn2;
    }
    __syncthreads();
  }

  float lp = lambda_p[h];
  float lam = log1pf(__expf(lp));   // softplus
  float inv1 = 1.f / l1, inv2 = 1.f / l2;

  bf16* dst = X + (size_t)token_q * 768 + h * 64 + g * 8;
  uint4 r;
  r.x = pack2(o1[0] * inv1 - lam * o2[0] * inv2, o1[1] * inv1 - lam * o2[1] * inv2);
  r.y = pack2(o1[2] * inv1 - lam * o2[2] * inv2, o1[3] * inv1 - lam * o2[3] * inv2);
  r.z = pack2(o1[4] * inv1 - lam * o2[4] * inv2, o1[5] * inv1 - lam * o2[5] * inv2);
  r.w = pack2(o1[6] * inv1 - lam * o2[6] * inv2, o1[7] * inv1 - lam * o2[7] * inv2);
  *reinterpret_cast<uint4*>(dst) = r;
}

// ---------------------------------------------------------------------------
extern "C" void kernel_launch(void* const* d_in, const int* in_sizes, int n_in,
                              void* d_out, int out_size, void* d_ws, size_t ws_size,
                              hipStream_t stream)
{
  const float* x        = (const float*)d_in[0];
  const float* Wq       = (const float*)d_in[1];
  const float* Wk       = (const float*)d_in[2];
  const float* Wv1      = (const float*)d_in[3];
  const float* Wv2      = (const float*)d_in[4];
  const float* lambda_p = (const float*)d_in[5];
  const float* Wo       = (const float*)d_in[6];
  const float* bo       = (const float*)d_in[7];
  float* out = (float*)d_out;

  // ws layout (bf16 elements)
  bf16* xb   = (bf16*)d_ws;                      // 4096*768
  bf16* Wqb  = xb   + (size_t)NTOK * 768;        // 1536*768
  bf16* Wkb  = Wqb  + (size_t)1536 * 768;        // 512*768
  bf16* Wv1b = Wkb  + (size_t)512 * 768;         // 256*768
  bf16* Wv2b = Wv1b + (size_t)256 * 768;         // 256*768
  bf16* Wob  = Wv2b + (size_t)256 * 768;         // 768*768
  bf16* qb   = Wob  + (size_t)768 * 768;         // 4096*1536
  bf16* kb   = qb   + (size_t)NTOK * 1536;       // 4096*512
  bf16* v1b  = kb   + (size_t)NTOK * 512;        // 4096*256
  bf16* v2b  = v1b  + (size_t)NTOK * 256;        // 4096*256
  bf16* Xb   = v2b  + (size_t)NTOK * 256;        // 4096*768

  dim3 blk(256);
  const int M = NTOK;

  cvt_f32_bf16<<<(NTOK * 768 / 4 + 255) / 256, blk, 0, stream>>>(x,   xb,   NTOK * 768 / 4);
  cvt_f32_bf16<<<(1536 * 768 / 4 + 255) / 256, blk, 0, stream>>>(Wq,  Wqb,  1536 * 768 / 4);
  cvt_f32_bf16<<<(512  * 768 / 4 + 255) / 256, blk, 0, stream>>>(Wk,  Wkb,  512 * 768 / 4);
  cvt_f32_bf16<<<(256  * 768 / 4 + 255) / 256, blk, 0, stream>>>(Wv1, Wv1b, 256 * 768 / 4);
  cvt_f32_bf16<<<(256  * 768 / 4 + 255) / 256, blk, 0, stream>>>(Wv2, Wv2b, 256 * 768 / 4);
  cvt_f32_bf16<<<(768  * 768 / 4 + 255) / 256, blk, 0, stream>>>(Wo,  Wob,  768 * 768 / 4);

  gemm_bt<bf16><<<dim3(1536 / 64, M / 64), blk, 0, stream>>>(xb, Wqb,  qb,  nullptr, M, 1536, DIM);
  gemm_bt<bf16><<<dim3(512  / 64, M / 64), blk, 0, stream>>>(xb, Wkb,  kb,  nullptr, M, 512,  DIM);
  gemm_bt<bf16><<<dim3(256  / 64, M / 64), blk, 0, stream>>>(xb, Wv1b, v1b, nullptr, M, 256,  DIM);
  gemm_bt<bf16><<<dim3(256  / 64, M / 64), blk, 0, stream>>>(xb, Wv2b, v2b, nullptr, M, 256,  DIM);

  rope_qknorm<<<(NQVEC + NKVEC) / 4, blk, 0, stream>>>(qb, kb);

  attn_fused<<<BATCH * NH * 32, blk, 0, stream>>>(qb, kb, v1b, v2b, lambda_p, Xb);

  gemm_bt<float><<<dim3(768 / 64, M / 64), blk, 0, stream>>>(Xb, Wob, out, bo, M, 768, DIM);
}

// Round 3
// 256.484 us; speedup vs baseline: 2.0109x; 2.0109x over previous
//
#include <hip/hip_runtime.h>
#include <hip/hip_bf16.h>

// Sizes fixed by the problem
#define BATCH 4
#define NSEQ  1024
#define DIM   768
#define NH    12
#define NKV   4
#define HD    64
#define NTOK  (BATCH*NSEQ)   // 4096

using bf16 = __hip_bfloat16;
typedef __attribute__((ext_vector_type(8))) short short8;
typedef __attribute__((ext_vector_type(4))) float floatx4;

__device__ __forceinline__ float b2f(short x) {
  unsigned u = ((unsigned)(unsigned short)x) << 16;
  return __builtin_bit_cast(float, u);
}
__device__ __forceinline__ unsigned short f2b(float f) {
  unsigned u = __builtin_bit_cast(unsigned, f);
  unsigned r = u + 0x7FFF + ((u >> 16) & 1);   // RNE
  return (unsigned short)(r >> 16);
}

// ---------------------------------------------------------------------------
// f32 -> bf16 convert (n multiple of 4)
// ---------------------------------------------------------------------------
__global__ __launch_bounds__(256) void cvt_f32_bf16(const float* __restrict__ src,
                                                    bf16* __restrict__ dst, int n4)
{
  int i = blockIdx.x * 256 + threadIdx.x;
  if (i < n4) {
    float4 f = reinterpret_cast<const float4*>(src)[i];
    ushort4 u;
    u.x = f2b(f.x); u.y = f2b(f.y); u.z = f2b(f.z); u.w = f2b(f.w);
    reinterpret_cast<ushort4*>(dst)[i] = u;
  }
}

// ---------------------------------------------------------------------------
// GEMM: Y[m,n] = sum_k A[m,k]*W[n,k] (+bias[n]); bf16 in, fp32 accum.
// ---------------------------------------------------------------------------
template <typename OUT>
__global__ __launch_bounds__(256) void gemm_bt(
    const bf16* __restrict__ A, const bf16* __restrict__ W,
    OUT* __restrict__ Y, const float* __restrict__ bias,
    int M, int Ncols, int K)
{
  __shared__ bf16 As[64][40];
  __shared__ bf16 Bs[64][40];
  const int bn = blockIdx.x, bm = blockIdx.y;
  const int t = threadIdx.x;
  const int wave = t >> 6, lane = t & 63;
  const int wm = wave >> 1, wn = wave & 1;
  const int quad = lane >> 4, lr = lane & 15;

  floatx4 acc[2][2] = {};

  const int arow = t >> 2, aseg = t & 3;
  const bf16* Aptr = A + (size_t)(bm * 64 + arow) * K + aseg * 8;
  const bf16* Wptr = W + (size_t)(bn * 64 + arow) * K + aseg * 8;

  for (int k0 = 0; k0 < K; k0 += 32) {
    short8 av = *reinterpret_cast<const short8*>(Aptr + k0);
    short8 wv = *reinterpret_cast<const short8*>(Wptr + k0);
    *reinterpret_cast<short8*>(&As[arow][aseg * 8]) = av;
    *reinterpret_cast<short8*>(&Bs[arow][aseg * 8]) = wv;
    __syncthreads();

    short8 a0 = *reinterpret_cast<const short8*>(&As[wm * 32 + lr][quad * 8]);
    short8 a1 = *reinterpret_cast<const short8*>(&As[wm * 32 + 16 + lr][quad * 8]);
    short8 b0 = *reinterpret_cast<const short8*>(&Bs[wn * 32 + lr][quad * 8]);
    short8 b1 = *reinterpret_cast<const short8*>(&Bs[wn * 32 + 16 + lr][quad * 8]);

    acc[0][0] = __builtin_amdgcn_mfma_f32_16x16x32_bf16(a0, b0, acc[0][0], 0, 0, 0);
    acc[0][1] = __builtin_amdgcn_mfma_f32_16x16x32_bf16(a0, b1, acc[0][1], 0, 0, 0);
    acc[1][0] = __builtin_amdgcn_mfma_f32_16x16x32_bf16(a1, b0, acc[1][0], 0, 0, 0);
    acc[1][1] = __builtin_amdgcn_mfma_f32_16x16x32_bf16(a1, b1, acc[1][1], 0, 0, 0);
    __syncthreads();
  }

  for (int tm = 0; tm < 2; ++tm)
    for (int tn = 0; tn < 2; ++tn)
      for (int r = 0; r < 4; ++r) {
        int row = bm * 64 + wm * 32 + tm * 16 + quad * 4 + r;
        int col = bn * 64 + wn * 32 + tn * 16 + lr;
        float v = acc[tm][tn][r];
        if (bias) v += bias[col];
        if constexpr (__is_same(OUT, float)) {
          Y[(size_t)row * Ncols + col] = v;
        } else {
          unsigned short ub = f2b(v);
          *(unsigned short*)&Y[(size_t)row * Ncols + col] = ub;
        }
      }
}

// ---------------------------------------------------------------------------
// RoPE (2D grid positions) + qk-norm, in place on q (4096x1536) and k (4096x512).
// ---------------------------------------------------------------------------
#define NQVEC (NTOK * 2 * NH)    // 98304
#define NKVEC (NTOK * 2 * NKV)   // 32768

__global__ __launch_bounds__(256) void rope_qknorm(bf16* __restrict__ q,
                                                   bf16* __restrict__ k)
{
  int wid = (blockIdx.x * 256 + threadIdx.x) >> 6;
  int lane = threadIdx.x & 63;
  bf16* ptr;
  int token;
  if (wid < NQVEC) {
    token = wid / 24;
    int rem = wid % 24;
    ptr = q + (size_t)token * 1536 + rem * 64;
  } else {
    int w2 = wid - NQVEC;
    token = w2 / 8;
    int rem = w2 % 8;
    ptr = k + (size_t)token * 512 + rem * 64;
  }
  int n = token & (NSEQ - 1);
  float pos = (lane < 32) ? (float)(n >> 5) : (float)(n & 31);
  int fi = lane & 31;
  float invf = exp2f(-(float)fi * (13.2877123795494f / 32.0f));
  float theta = pos * invf;
  float sn, cs;
  sincosf(theta, &sn, &cs);

  float val = b2f(*(const short*)&ptr[lane]);
  float partner = __shfl_xor(val, 1);
  float rot = (lane & 1) ? partner : -partner;
  float r = val * cs + rot * sn;

  float ss = r * r;
  #pragma unroll
  for (int off = 1; off < 64; off <<= 1) ss += __shfl_xor(ss, off);
  float outv = r / (sqrtf(ss) + 1e-6f);
  unsigned short ub = f2b(outv);
  *(unsigned short*)&ptr[lane] = ub;
}

// ---------------------------------------------------------------------------
// V transpose: v[4096 tok][256] -> vt[b][kvh][64 d][1024 n]
// ---------------------------------------------------------------------------
__global__ __launch_bounds__(256) void transpose_v(const bf16* __restrict__ v,
                                                   bf16* __restrict__ vt)
{
  __shared__ bf16 tile[64][68];
  int blk = blockIdx.x;              // b*64 + kvh*16 + ntile
  int ntile = blk & 15;
  int kvh = (blk >> 4) & 3;
  int b = blk >> 6;
  int t = threadIdx.x;
  int n0 = ntile * 64;

  #pragma unroll
  for (int l = 0; l < 4; ++l) {
    int nl = (t >> 4) + l * 16;
    int dl = (t & 15) * 4;
    ushort4 val = *reinterpret_cast<const ushort4*>(
        v + (size_t)(b * 1024 + n0 + nl) * 256 + kvh * 64 + dl);
    *reinterpret_cast<ushort4*>(&tile[nl][dl]) = val;
  }
  __syncthreads();
  #pragma unroll
  for (int l = 0; l < 4; ++l) {
    int dl = (t >> 4) + l * 16;
    int nl = (t & 15) * 4;
    ushort4 val;
    val.x = *(const unsigned short*)&tile[nl + 0][dl];
    val.y = *(const unsigned short*)&tile[nl + 1][dl];
    val.z = *(const unsigned short*)&tile[nl + 2][dl];
    val.w = *(const unsigned short*)&tile[nl + 3][dl];
    *reinterpret_cast<ushort4*>(
        vt + (size_t)((b * 4 + kvh) * 64 + dl) * 1024 + n0 + nl) = val;
  }
}

// ---------------------------------------------------------------------------
// MFMA flash attention, windowed, both streams + differential combine.
// Block = (b,h,qh), 128 threads = 2 waves (wave s = stream s).
// S = Q.K^T via mfma (A=Q, B=K direct from global); row softmax (C-layout
// rows = queries -> stats lane-aligned with O); P via LDS; PV with B=Vt
// frags direct from pre-transposed global V.
// ---------------------------------------------------------------------------
__global__ __launch_bounds__(128, 3) void attn_mfma(
    const bf16* __restrict__ q, const bf16* __restrict__ k,
    const bf16* __restrict__ v1t, const bf16* __restrict__ v2t,
    const float* __restrict__ lambda_p, bf16* __restrict__ X)
{
  __shared__ __align__(16) char smem_raw[13440];

  const int bid = blockIdx.x;
  const int qh = bid & 31;
  const int hb = bid >> 5;          // h + 12*b
  const int h  = hb % 12;
  const int b  = hb / 12;
  const int kvh = h / 3;

  const int t = threadIdx.x;
  const int s = t >> 6;             // wave index = stream
  const int lane = t & 63;
  const int quad = lane >> 4, lr = lane & 15;

  bf16* Pl = (bf16*)smem_raw + s * 1280;   // [32][40] bf16 per wave

  const int tok0 = b * NSEQ + qh * 32;

  // Q fragments: A[m=lr (+16mt)][k=quad*8+j (+32ks)]
  short8 qf[2][2];
  #pragma unroll
  for (int mt = 0; mt < 2; ++mt)
    #pragma unroll
    for (int ks = 0; ks < 2; ++ks)
      qf[mt][ks] = *reinterpret_cast<const short8*>(
          q + (size_t)(tok0 + mt * 16 + lr) * 1536 + s * 768 + h * 64 + ks * 32 + quad * 8);

  // Precompute column mask addend: S[q][km], q=mt*16+quad*4+r, km=nt*16+lr
  float madd[2][2][4];
  #pragma unroll
  for (int mt = 0; mt < 2; ++mt)
    #pragma unroll
    for (int nt = 0; nt < 2; ++nt)
      #pragma unroll
      for (int r = 0; r < 4; ++r) {
        int qq = mt * 16 + quad * 4 + r;
        int km = nt * 16 + lr;
        int d = km - qq; if (d < 0) d = -d;
        madd[mt][nt][r] = (d <= 8) ? 0.f : -1e30f;
      }

  floatx4 O[2][4] = {};
  float mrow[2][4], lrow[2][4];
  #pragma unroll
  for (int mt = 0; mt < 2; ++mt)
    #pragma unroll
    for (int r = 0; r < 4; ++r) { mrow[mt][r] = -1e30f; lrow[mt][r] = 0.f; }

  const int kh0 = (qh > 8) ? qh - 8 : 0;
  const int kh1 = (qh < 23) ? qh + 8 : 31;
  const bf16* vbase = (s ? v2t : v1t) + (size_t)((b * 4 + kvh) * 64) * 1024;

  for (int kh = kh0; kh <= kh1; ++kh) {
    const int tk0 = b * NSEQ + kh * 32;

    // K fragments: B[n=lr (+16nt)][k=quad*8+j (+32ks)]
    short8 kf[2][2];
    #pragma unroll
    for (int nt = 0; nt < 2; ++nt)
      #pragma unroll
      for (int ks = 0; ks < 2; ++ks)
        kf[nt][ks] = *reinterpret_cast<const short8*>(
            k + (size_t)(tk0 + nt * 16 + lr) * 512 + s * 256 + kvh * 64 + ks * 32 + quad * 8);

    // Vt fragments: B[n=d=lr (+16ntd)][k=key=quad*8+j]
    short8 vf[4];
    #pragma unroll
    for (int ntd = 0; ntd < 4; ++ntd)
      vf[ntd] = *reinterpret_cast<const short8*>(
          vbase + (size_t)(ntd * 16 + lr) * 1024 + kh * 32 + quad * 8);

    // S = Q.K^T
    floatx4 S[2][2] = {};
    #pragma unroll
    for (int ks = 0; ks < 2; ++ks) {
      S[0][0] = __builtin_amdgcn_mfma_f32_16x16x32_bf16(qf[0][ks], kf[0][ks], S[0][0], 0, 0, 0);
      S[0][1] = __builtin_amdgcn_mfma_f32_16x16x32_bf16(qf[0][ks], kf[1][ks], S[0][1], 0, 0, 0);
      S[1][0] = __builtin_amdgcn_mfma_f32_16x16x32_bf16(qf[1][ks], kf[0][ks], S[1][0], 0, 0, 0);
      S[1][1] = __builtin_amdgcn_mfma_f32_16x16x32_bf16(qf[1][ks], kf[1][ks], S[1][1], 0, 0, 0);
    }

    // scale + mask
    #pragma unroll
    for (int mt = 0; mt < 2; ++mt)
      #pragma unroll
      for (int nt = 0; nt < 2; ++nt)
        #pragma unroll
        for (int r = 0; r < 4; ++r)
          S[mt][nt][r] = fmaf(S[mt][nt][r], 0.125f, madd[mt][nt][r]);

    // row max (rows=queries, spread across lr lanes in 16-lane groups)
    float rmax[2][4];
    #pragma unroll
    for (int mt = 0; mt < 2; ++mt)
      #pragma unroll
      for (int r = 0; r < 4; ++r)
        rmax[mt][r] = fmaxf(S[mt][0][r], S[mt][1][r]);
    #pragma unroll
    for (int off = 1; off < 16; off <<= 1)
      #pragma unroll
      for (int mt = 0; mt < 2; ++mt)
        #pragma unroll
        for (int r = 0; r < 4; ++r)
          rmax[mt][r] = fmaxf(rmax[mt][r], __shfl_xor(rmax[mt][r], off));

    float corr[2][4];
    #pragma unroll
    for (int mt = 0; mt < 2; ++mt)
      #pragma unroll
      for (int r = 0; r < 4; ++r) {
        float mn = fmaxf(mrow[mt][r], rmax[mt][r]);
        corr[mt][r] = __expf(mrow[mt][r] - mn);
        mrow[mt][r] = mn;
      }

    // P = exp(S - m), write to LDS (A-layout staging), accumulate row sums
    float psum[2][4] = {};
    #pragma unroll
    for (int mt = 0; mt < 2; ++mt)
      #pragma unroll
      for (int nt = 0; nt < 2; ++nt)
        #pragma unroll
        for (int r = 0; r < 4; ++r) {
          float p = __expf(S[mt][nt][r] - mrow[mt][r]);
          psum[mt][r] += p;
          *(unsigned short*)&Pl[(mt * 16 + quad * 4 + r) * 40 + nt * 16 + lr] = f2b(p);
        }
    #pragma unroll
    for (int off = 1; off < 16; off <<= 1)
      #pragma unroll
      for (int mt = 0; mt < 2; ++mt)
        #pragma unroll
        for (int r = 0; r < 4; ++r)
          psum[mt][r] += __shfl_xor(psum[mt][r], off);

    #pragma unroll
    for (int mt = 0; mt < 2; ++mt)
      #pragma unroll
      for (int r = 0; r < 4; ++r)
        lrow[mt][r] = lrow[mt][r] * corr[mt][r] + psum[mt][r];

    // rescale O (rows lane-aligned with corr)
    #pragma unroll
    for (int mt = 0; mt < 2; ++mt)
      #pragma unroll
      for (int ntd = 0; ntd < 4; ++ntd)
        #pragma unroll
        for (int r = 0; r < 4; ++r)
          O[mt][ntd][r] *= corr[mt][r];

    // PV: A = P (from LDS), B = Vt frags
    short8 pf[2];
    #pragma unroll
    for (int mt = 0; mt < 2; ++mt)
      pf[mt] = *reinterpret_cast<const short8*>(&Pl[(mt * 16 + lr) * 40 + quad * 8]);

    #pragma unroll
    for (int mt = 0; mt < 2; ++mt)
      #pragma unroll
      for (int ntd = 0; ntd < 4; ++ntd)
        O[mt][ntd] = __builtin_amdgcn_mfma_f32_16x16x32_bf16(pf[mt], vf[ntd], O[mt][ntd], 0, 0, 0);
  }

  // normalize
  #pragma unroll
  for (int mt = 0; mt < 2; ++mt)
    #pragma unroll
    for (int r = 0; r < 4; ++r)
      lrow[mt][r] = 1.f / lrow[mt][r];
  #pragma unroll
  for (int mt = 0; mt < 2; ++mt)
    #pragma unroll
    for (int ntd = 0; ntd < 4; ++ntd)
      #pragma unroll
      for (int r = 0; r < 4; ++r)
        O[mt][ntd][r] *= lrow[mt][r];

  // combine: X = O1 - softplus(lambda)*O2
  float* Of = (float*)smem_raw;               // [32][68] f32
  bf16* Xs = (bf16*)(smem_raw + 8704);        // [32][72] bf16

  __syncthreads();
  if (s == 1) {
    #pragma unroll
    for (int mt = 0; mt < 2; ++mt)
      #pragma unroll
      for (int ntd = 0; ntd < 4; ++ntd)
        #pragma unroll
        for (int r = 0; r < 4; ++r)
          Of[(mt * 16 + quad * 4 + r) * 68 + ntd * 16 + lr] = O[mt][ntd][r];
  }
  __syncthreads();
  if (s == 0) {
    float lam = log1pf(__expf(lambda_p[h]));
    #pragma unroll
    for (int mt = 0; mt < 2; ++mt)
      #pragma unroll
      for (int ntd = 0; ntd < 4; ++ntd)
        #pragma unroll
        for (int r = 0; r < 4; ++r) {
          float o2 = Of[(mt * 16 + quad * 4 + r) * 68 + ntd * 16 + lr];
          float xv = O[mt][ntd][r] - lam * o2;
          *(unsigned short*)&Xs[(mt * 16 + quad * 4 + r) * 72 + ntd * 16 + lr] = f2b(xv);
        }
  }
  __syncthreads();

  // coalesced store of the 32x64 bf16 tile
  #pragma unroll
  for (int slot = 0; slot < 2; ++slot) {
    int idx = slot * 128 + t;
    int row = idx >> 3, seg = idx & 7;
    short8 xv = *reinterpret_cast<const short8*>(&Xs[row * 72 + seg * 8]);
    *reinterpret_cast<short8*>(X + (size_t)(tok0 + row) * 768 + h * 64 + seg * 8) = xv;
  }
}

// ---------------------------------------------------------------------------
extern "C" void kernel_launch(void* const* d_in, const int* in_sizes, int n_in,
                              void* d_out, int out_size, void* d_ws, size_t ws_size,
                              hipStream_t stream)
{
  const float* x        = (const float*)d_in[0];
  const float* Wq       = (const float*)d_in[1];
  const float* Wk       = (const float*)d_in[2];
  const float* Wv1      = (const float*)d_in[3];
  const float* Wv2      = (const float*)d_in[4];
  const float* lambda_p = (const float*)d_in[5];
  const float* Wo       = (const float*)d_in[6];
  const float* bo       = (const float*)d_in[7];
  float* out = (float*)d_out;

  bf16* xb   = (bf16*)d_ws;                      // 4096*768
  bf16* Wqb  = xb   + (size_t)NTOK * 768;        // 1536*768
  bf16* Wkb  = Wqb  + (size_t)1536 * 768;        // 512*768
  bf16* Wv1b = Wkb  + (size_t)512 * 768;         // 256*768
  bf16* Wv2b = Wv1b + (size_t)256 * 768;         // 256*768
  bf16* Wob  = Wv2b + (size_t)256 * 768;         // 768*768
  bf16* qb   = Wob  + (size_t)768 * 768;         // 4096*1536
  bf16* kb   = qb   + (size_t)NTOK * 1536;       // 4096*512
  bf16* v1b  = kb   + (size_t)NTOK * 512;        // 4096*256
  bf16* v2b  = v1b  + (size_t)NTOK * 256;        // 4096*256
  bf16* Xb   = v2b  + (size_t)NTOK * 256;        // 4096*768
  bf16* v1t  = Xb   + (size_t)NTOK * 768;        // 4*4*64*1024
  bf16* v2t  = v1t  + (size_t)NTOK * 256;        // 4*4*64*1024

  dim3 blk(256);
  const int M = NTOK;

  cvt_f32_bf16<<<(NTOK * 768 / 4 + 255) / 256, blk, 0, stream>>>(x,   xb,   NTOK * 768 / 4);
  cvt_f32_bf16<<<(1536 * 768 / 4 + 255) / 256, blk, 0, stream>>>(Wq,  Wqb,  1536 * 768 / 4);
  cvt_f32_bf16<<<(512  * 768 / 4 + 255) / 256, blk, 0, stream>>>(Wk,  Wkb,  512 * 768 / 4);
  cvt_f32_bf16<<<(256  * 768 / 4 + 255) / 256, blk, 0, stream>>>(Wv1, Wv1b, 256 * 768 / 4);
  cvt_f32_bf16<<<(256  * 768 / 4 + 255) / 256, blk, 0, stream>>>(Wv2, Wv2b, 256 * 768 / 4);
  cvt_f32_bf16<<<(768  * 768 / 4 + 255) / 256, blk, 0, stream>>>(Wo,  Wob,  768 * 768 / 4);

  gemm_bt<bf16><<<dim3(1536 / 64, M / 64), blk, 0, stream>>>(xb, Wqb,  qb,  nullptr, M, 1536, DIM);
  gemm_bt<bf16><<<dim3(512  / 64, M / 64), blk, 0, stream>>>(xb, Wkb,  kb,  nullptr, M, 512,  DIM);
  gemm_bt<bf16><<<dim3(256  / 64, M / 64), blk, 0, stream>>>(xb, Wv1b, v1b, nullptr, M, 256,  DIM);
  gemm_bt<bf16><<<dim3(256  / 64, M / 64), blk, 0, stream>>>(xb, Wv2b, v2b, nullptr, M, 256,  DIM);

  rope_qknorm<<<(NQVEC + NKVEC) / 4, blk, 0, stream>>>(qb, kb);

  transpose_v<<<256, blk, 0, stream>>>(v1b, v1t);
  transpose_v<<<256, blk, 0, stream>>>(v2b, v2t);

  attn_mfma<<<BATCH * NH * 32, dim3(128), 0, stream>>>(qb, kb, v1t, v2t, lambda_p, Xb);

  gemm_bt<float><<<dim3(768 / 64, M / 64), blk, 0, stream>>>(Xb, Wob, out, bo, M, 768, DIM);
}